// Round 2
// baseline (49.819 us; speedup 1.0000x reference)
//
#include <hip/hip_runtime.h>

// PrototypeTripletRankingLoss: B=1024, K=127, D=512, fp32.
// loss = mean_b mean_k max(0, 0.2 + cos(ref_b, neg_bk) - cos(ref_b, pos_b))
// with each norm clamped to >= 1e-8 (torch cosine_similarity semantics).
//
// R1 restructure: 4 negatives per wave-iteration, 16 lanes per negative
// (lane = 16*sub + sl, each lane owns 32 floats of D=512). Butterfly reduce
// is 4 steps within 16-lane groups and reduces 4 k's at once: 2 DS ops per k
// instead of 12 -> DS pipe no longer co-limits the streaming loads.

#define NB 1024
#define NK 127
#define ND 512
#define MARGIN 0.2f
#define CEPS 1e-8f

__device__ __forceinline__ float dot4(const float4 a, const float4 b) {
    return a.x * b.x + a.y * b.y + a.z * b.z + a.w * b.w;
}

__global__ __launch_bounds__(256) void triplet_main(
    const float* __restrict__ ref, const float* __restrict__ pos,
    const float* __restrict__ neg, float* __restrict__ partial)
{
    const int b    = blockIdx.x;
    const int tid  = threadIdx.x;
    const int wave = tid >> 6;
    const int lane = tid & 63;
    const int sub  = lane >> 4;   // which of 4 k's in the group
    const int sl   = lane & 15;   // 16 lanes per k; lane owns floats [sl*4 + j*64]

    const float* refr = ref + (size_t)b * ND;
    const float* posr = pos + (size_t)b * ND;

    // Per-lane ref fragment: 32 floats (depends only on sl; replicated across sub).
    float4 r[8];
    #pragma unroll
    for (int j = 0; j < 8; ++j) r[j] = *(const float4*)(refr + sl * 4 + j * 64);

    float rs = 0.0f, ps = 0.0f, pd = 0.0f;
    #pragma unroll
    for (int j = 0; j < 8; ++j) {
        const float4 p = *(const float4*)(posr + sl * 4 + j * 64);
        rs += dot4(r[j], r[j]);
        ps += dot4(p, p);
        pd += dot4(r[j], p);
    }
    #pragma unroll
    for (int off = 1; off <= 8; off <<= 1) {
        rs += __shfl_xor(rs, off);
        ps += __shfl_xor(ps, off);
        pd += __shfl_xor(pd, off);
    }

    const float inv_r   = 1.0f / fmaxf(sqrtf(rs), CEPS);
    const float pos_sim = pd * inv_r * (1.0f / fmaxf(sqrtf(ps), CEPS));

    float acc = 0.0f;
    const float* negb = neg + (size_t)b * (NK * ND);

    // 32 groups of 4 k's (last slot masked); wave w takes groups w, w+4, ...
    for (int g = wave; g < 32; g += 4) {
        const int  k     = 4 * g + sub;
        const bool valid = (k < NK);
        const int  kk    = valid ? k : (NK - 1);   // clamp to a safe row
        const float* nr  = negb + (size_t)kk * ND + sl * 4;

        float4 n[8];
        #pragma unroll
        for (int j = 0; j < 8; ++j) n[j] = *(const float4*)(nr + j * 64);

        float nd = 0.0f, ns = 0.0f;
        #pragma unroll
        for (int j = 0; j < 8; ++j) {
            nd += dot4(r[j], n[j]);
            ns += dot4(n[j], n[j]);
        }
        #pragma unroll
        for (int off = 1; off <= 8; off <<= 1) {
            nd += __shfl_xor(nd, off);
            ns += __shfl_xor(ns, off);
        }
        const float sim = nd * inv_r * (1.0f / fmaxf(sqrtf(ns), CEPS));
        acc += valid ? fmaxf(MARGIN + sim - pos_sim, 0.0f) : 0.0f;
    }

    // acc is identical across the 16 lanes of each quarter; sum the 4 quarters.
    acc += __shfl_xor(acc, 16);
    acc += __shfl_xor(acc, 32);

    __shared__ float sacc[4];
    if (lane == 0) sacc[wave] = acc;
    __syncthreads();
    if (tid == 0) partial[b] = (sacc[0] + sacc[1]) + (sacc[2] + sacc[3]);
}

// Deterministic final reduction: 1 block, 256 threads over 1024 partials.
__global__ __launch_bounds__(256) void triplet_reduce(
    const float* __restrict__ partial, float* __restrict__ out)
{
    float s = 0.0f;
    for (int i = threadIdx.x; i < NB; i += 256) s += partial[i];
    #pragma unroll
    for (int off = 32; off; off >>= 1) s += __shfl_xor(s, off);
    __shared__ float w[4];
    if ((threadIdx.x & 63) == 0) w[threadIdx.x >> 6] = s;
    __syncthreads();
    if (threadIdx.x == 0)
        out[0] = ((w[0] + w[1]) + (w[2] + w[3])) * (1.0f / ((float)NB * (float)NK));
}

extern "C" void kernel_launch(void* const* d_in, const int* in_sizes, int n_in,
                              void* d_out, int out_size, void* d_ws, size_t ws_size,
                              hipStream_t stream) {
    const float* ref = (const float*)d_in[0];
    const float* pos = (const float*)d_in[1];
    const float* neg = (const float*)d_in[2];
    float* out     = (float*)d_out;
    float* partial = (float*)d_ws;   // NB floats = 4 KiB scratch

    triplet_main<<<NB, 256, 0, stream>>>(ref, pos, neg, partial);
    triplet_reduce<<<1, 256, 0, stream>>>(partial, out);
}